// Round 8
// baseline (3218.813 us; speedup 1.0000x reference)
//
#include <hip/hip_runtime.h>

// CRF forward on MI355X — R6: dual-chain interval (32 batches/block).
//
// R5 post-mortem: kernel is LATENCY-bound on the V->V recurrence (all pipes
// <40% busy; barrier-lockstepped waves stall together). In-step Sigma put the
// tree on the critical path (+420 cyc/step); inline-asm v_exp_f32 (TRANS
// result-use hazard) is the prime absmax=32 suspect. Both reverted.
//
// R6 keeps R4b's verified per-step machinery (expf, rcp-g, RTE f16 casts,
// 4x2 MFMA chains, lgkm-only barrier) and fills the recurrence bubbles with a
// SECOND independent 16-batch chain: 32 batches/block, chains A and B share
// the E fragments and one barrier/step. Each wave's stream: readA|readB ->
// mfmaA -> treeA (VALU, hides under MFMA) -> mfmaB -> epiA/writeA ->
// epiB/writeB -> bar. A's MFMA-completion wait is covered by B's issue.
// Sigma from in-register fp16 tree over the b-fragments (provably exact:
// any normalizer cancels as long as the SAME value is logged into Lam).

typedef _Float16 f16x8 __attribute__((ext_vector_type(8)));
typedef _Float16 f16x4 __attribute__((ext_vector_type(4)));
typedef _Float16 f16x2 __attribute__((ext_vector_type(2)));
typedef float    f32x4 __attribute__((ext_vector_type(4)));

#define TT 2048
#define KK 256
#define NTH 512
#define SOS_IDX 2

#define MFMA(A, B, C) __builtin_amdgcn_mfma_f32_16x16x32_f16((A), (B), (C), 0, 0, 0)

__global__ __launch_bounds__(NTH, 2)
void crf_fwd_kernel(const float* __restrict__ y, const float* __restrict__ mask,
                    const float* __restrict__ trans, float* __restrict__ out)
{
    const int tid = threadIdx.x;
    const int w = tid >> 6, l = tid & 63;
    const int c = l & 15;            // column = batch-in-group (also A-row-in-tile)
    const int s = l >> 4;            // k-subgroup 0..3
    const int sw = (c & 7) << 4;     // LDS XOR swizzle (bits 4..6 of byte offset)
    const int bb = blockIdx.x * 32;  // 32 batches per block: A = bb.., B = bb+16..

    __shared__ __align__(16) char VA[2][16 * 512];   // chain A prob vectors
    __shared__ __align__(16) char VB[2][16 * 512];   // chain B prob vectors
    __shared__ float Lcs[32];

    // ---- E fragments (shared by both chains): af{0,1}[kt] rows 32w+16rt+c
    f16x8 af0[8], af1[8];
    {
        const float* t0 = trans + (size_t)(32 * w + c) * KK + 8 * s;
        const float* t1 = t0 + 16 * KK;
        #pragma unroll
        for (int kt = 0; kt < 8; ++kt) {
            float4 a0 = *(const float4*)(t0 + 32 * kt);
            float4 a1 = *(const float4*)(t0 + 32 * kt + 4);
            float4 b0 = *(const float4*)(t1 + 32 * kt);
            float4 b1 = *(const float4*)(t1 + 32 * kt + 4);
            f16x8 A, Bv;
            A[0] = (_Float16)__expf(a0.x); A[1] = (_Float16)__expf(a0.y);
            A[2] = (_Float16)__expf(a0.z); A[3] = (_Float16)__expf(a0.w);
            A[4] = (_Float16)__expf(a1.x); A[5] = (_Float16)__expf(a1.y);
            A[6] = (_Float16)__expf(a1.z); A[7] = (_Float16)__expf(a1.w);
            Bv[0] = (_Float16)__expf(b0.x); Bv[1] = (_Float16)__expf(b0.y);
            Bv[2] = (_Float16)__expf(b0.z); Bv[3] = (_Float16)__expf(b0.w);
            Bv[4] = (_Float16)__expf(b1.x); Bv[5] = (_Float16)__expf(b1.y);
            Bv[6] = (_Float16)__expf(b1.z); Bv[7] = (_Float16)__expf(b1.w);
            af0[kt] = A; af1[kt] = Bv;
        }
    }

    // ---- lengths: 16 threads per batch (32 batches)
    {
        const int cq = tid >> 4, q = tid & 15;
        const float* mrow = mask + (size_t)(bb + cq) * TT;
        float ls = 0.f;
        #pragma unroll
        for (int i = 0; i < TT / 16; ++i) ls += mrow[q + 16 * i];
        #pragma unroll
        for (int off = 8; off >= 1; off >>= 1) ls += __shfl_xor(ls, off, 64);
        if (q == 0) Lcs[cq] = ls;
    }

    // ---- init both chains: V0 = one-hot(SOS); W in f32 regs
    const int r0 = 32 * w + 4 * s;
    float WA0 = (r0 + 0 == SOS_IDX) ? 1.f : 0.f;
    float WA1 = (r0 + 1 == SOS_IDX) ? 1.f : 0.f;
    float WA2 = (r0 + 2 == SOS_IDX) ? 1.f : 0.f;
    float WA3 = (r0 + 3 == SOS_IDX) ? 1.f : 0.f;
    float WA4 = (r0 + 16 == SOS_IDX) ? 1.f : 0.f;
    float WA5 = (r0 + 17 == SOS_IDX) ? 1.f : 0.f;
    float WA6 = (r0 + 18 == SOS_IDX) ? 1.f : 0.f;
    float WA7 = (r0 + 19 == SOS_IDX) ? 1.f : 0.f;
    float WB0 = WA0, WB1 = WA1, WB2 = WA2, WB3 = WA3;
    float WB4 = WA4, WB5 = WA5, WB6 = WA6, WB7 = WA7;
    {
        f16x4 h0 = {(_Float16)WA0, (_Float16)WA1, (_Float16)WA2, (_Float16)WA3};
        f16x4 h1 = {(_Float16)WA4, (_Float16)WA5, (_Float16)WA6, (_Float16)WA7};
        char* wa = VA[0] + (c << 9);
        char* wb = VB[0] + (c << 9);
        *(f16x4*)(wa + ((64 * w + 8 * s) ^ sw))      = h0;
        *(f16x4*)(wa + ((64 * w + 32 + 8 * s) ^ sw)) = h1;
        *(f16x4*)(wb + ((64 * w + 8 * s) ^ sw))      = h0;
        *(f16x4*)(wb + ((64 * w + 32 + 8 * s) ^ sw)) = h1;
    }
    __syncthreads();

    float Tm = 0.f;
    #pragma unroll
    for (int i = 0; i < 32; ++i) Tm = fmaxf(Tm, Lcs[i]);
    const int Tmax = (int)(Tm + 0.5f);
    const int LciA = (int)(Lcs[c] + 0.5f);
    const int LciB = (int)(Lcs[16 + c] + 0.5f);

    // ---- y prefetch (2 ahead, ping-pong per chain)
    const float* ybA = y + (size_t)(bb + c) * (TT * KK) + 32 * w + 4 * s;
    const float* ybB = ybA + (size_t)16 * TT * KK;
    float4 yAa0 = *(const float4*)(ybA);
    float4 yAa1 = *(const float4*)(ybA + 16);
    float4 yBa0 = *(const float4*)(ybB);
    float4 yBa1 = *(const float4*)(ybB + 16);
    const int t1i = (Tmax > 1) ? 1 : 0;
    float4 yAb0 = *(const float4*)(ybA + (size_t)t1i * KK);
    float4 yAb1 = *(const float4*)(ybA + (size_t)t1i * KK + 16);
    float4 yBb0 = *(const float4*)(ybB + (size_t)t1i * KK);
    float4 yBb1 = *(const float4*)(ybB + (size_t)t1i * KK + 16);
    float LamA = 0.f, LamB = 0.f;

#define INTERVAL(PAR, YA0, YA1, YB0, YB1, TS)                                    \
  {                                                                              \
    const int t_ = (TS);                                                         \
    /* ---- chain A: read + MFMA ---- */                                         \
    const char* va_ = VA[PAR] + (c << 9);                                        \
    f16x8 a0 = *(const f16x8*)(va_ + ((0   + (s << 4)) ^ sw));                   \
    f16x8 a1 = *(const f16x8*)(va_ + ((64  + (s << 4)) ^ sw));                   \
    f16x8 a2 = *(const f16x8*)(va_ + ((128 + (s << 4)) ^ sw));                   \
    f16x8 a3 = *(const f16x8*)(va_ + ((192 + (s << 4)) ^ sw));                   \
    f16x8 a4 = *(const f16x8*)(va_ + ((256 + (s << 4)) ^ sw));                   \
    f16x8 a5 = *(const f16x8*)(va_ + ((320 + (s << 4)) ^ sw));                   \
    f16x8 a6 = *(const f16x8*)(va_ + ((384 + (s << 4)) ^ sw));                   \
    f16x8 a7 = *(const f16x8*)(va_ + ((448 + (s << 4)) ^ sw));                   \
    f32x4 zz = {0.f, 0.f, 0.f, 0.f};                                             \
    f32x4 cA0a = zz, cA0b = zz, cA1a = zz, cA1b = zz;                            \
    cA0a = MFMA(af0[0], a0, cA0a); cA1a = MFMA(af1[0], a0, cA1a);                \
    cA0b = MFMA(af0[4], a4, cA0b); cA1b = MFMA(af1[4], a4, cA1b);                \
    cA0a = MFMA(af0[1], a1, cA0a); cA1a = MFMA(af1[1], a1, cA1a);                \
    cA0b = MFMA(af0[5], a5, cA0b); cA1b = MFMA(af1[5], a5, cA1b);                \
    cA0a = MFMA(af0[2], a2, cA0a); cA1a = MFMA(af1[2], a2, cA1a);                \
    cA0b = MFMA(af0[6], a6, cA0b); cA1b = MFMA(af1[6], a6, cA1b);                \
    cA0a = MFMA(af0[3], a3, cA0a); cA1a = MFMA(af1[3], a3, cA1a);                \
    cA0b = MFMA(af0[7], a7, cA0b); cA1b = MFMA(af1[7], a7, cA1b);                \
    /* ---- chain A: Sigma tree (VALU, hides under MFMA issue) ---- */           \
    f16x8 tA = ((a0 + a1) + (a2 + a3)) + ((a4 + a5) + (a6 + a7));                \
    f16x2 uA0 = {tA[0], tA[1]}, uA1 = {tA[2], tA[3]};                            \
    f16x2 uA2 = {tA[4], tA[5]}, uA3 = {tA[6], tA[7]};                            \
    f16x2 uuA = (uA0 + uA1) + (uA2 + uA3);                                       \
    float SgA = (float)uuA[0] + (float)uuA[1];                                   \
    SgA += __shfl_xor(SgA, 16, 64);                                              \
    SgA += __shfl_xor(SgA, 32, 64);                                              \
    float gA  = 0.03125f * __builtin_amdgcn_rcpf(SgA);                           \
    float lgA = __log2f(SgA);                                                    \
    /* ---- chain B: read + MFMA ---- */                                         \
    const char* vb_ = VB[PAR] + (c << 9);                                        \
    f16x8 b0 = *(const f16x8*)(vb_ + ((0   + (s << 4)) ^ sw));                   \
    f16x8 b1 = *(const f16x8*)(vb_ + ((64  + (s << 4)) ^ sw));                   \
    f16x8 b2 = *(const f16x8*)(vb_ + ((128 + (s << 4)) ^ sw));                   \
    f16x8 b3 = *(const f16x8*)(vb_ + ((192 + (s << 4)) ^ sw));                   \
    f16x8 b4 = *(const f16x8*)(vb_ + ((256 + (s << 4)) ^ sw));                   \
    f16x8 b5 = *(const f16x8*)(vb_ + ((320 + (s << 4)) ^ sw));                   \
    f16x8 b6 = *(const f16x8*)(vb_ + ((384 + (s << 4)) ^ sw));                   \
    f16x8 b7 = *(const f16x8*)(vb_ + ((448 + (s << 4)) ^ sw));                   \
    f32x4 cB0a = zz, cB0b = zz, cB1a = zz, cB1b = zz;                            \
    cB0a = MFMA(af0[0], b0, cB0a); cB1a = MFMA(af1[0], b0, cB1a);                \
    cB0b = MFMA(af0[4], b4, cB0b); cB1b = MFMA(af1[4], b4, cB1b);                \
    cB0a = MFMA(af0[1], b1, cB0a); cB1a = MFMA(af1[1], b1, cB1a);                \
    cB0b = MFMA(af0[5], b5, cB0b); cB1b = MFMA(af1[5], b5, cB1b);                \
    cB0a = MFMA(af0[2], b2, cB0a); cB1a = MFMA(af1[2], b2, cB1a);                \
    cB0b = MFMA(af0[6], b6, cB0b); cB1b = MFMA(af1[6], b6, cB1b);                \
    cB0a = MFMA(af0[3], b3, cB0a); cB1a = MFMA(af1[3], b3, cB1a);                \
    cB0b = MFMA(af0[7], b7, cB0b); cB1b = MFMA(af1[7], b7, cB1b);                \
    f16x8 tB = ((b0 + b1) + (b2 + b3)) + ((b4 + b5) + (b6 + b7));                \
    f16x2 uB0 = {tB[0], tB[1]}, uB1 = {tB[2], tB[3]};                            \
    f16x2 uB2 = {tB[4], tB[5]}, uB3 = {tB[6], tB[7]};                            \
    f16x2 uuB = (uB0 + uB1) + (uB2 + uB3);                                       \
    float SgB = (float)uuB[0] + (float)uuB[1];                                   \
    SgB += __shfl_xor(SgB, 16, 64);                                              \
    SgB += __shfl_xor(SgB, 32, 64);                                              \
    float gB  = 0.03125f * __builtin_amdgcn_rcpf(SgB);                           \
    float lgB = __log2f(SgB);                                                    \
    /* ---- epilogue A (stall on accA covered by B's MFMA issue) ---- */         \
    const bool onA = (t_ < LciA);                                                \
    f32x4 qA0 = cA0a + cA0b, qA1 = cA1a + cA1b;                                  \
    float nA0 = onA ? __expf(YA0.x) * qA0[0] * gA : WA0;                         \
    float nA1 = onA ? __expf(YA0.y) * qA0[1] * gA : WA1;                         \
    float nA2 = onA ? __expf(YA0.z) * qA0[2] * gA : WA2;                         \
    float nA3 = onA ? __expf(YA0.w) * qA0[3] * gA : WA3;                         \
    float nA4 = onA ? __expf(YA1.x) * qA1[0] * gA : WA4;                         \
    float nA5 = onA ? __expf(YA1.y) * qA1[1] * gA : WA5;                         \
    float nA6 = onA ? __expf(YA1.z) * qA1[2] * gA : WA6;                         \
    float nA7 = onA ? __expf(YA1.w) * qA1[3] * gA : WA7;                         \
    WA0 = nA0; WA1 = nA1; WA2 = nA2; WA3 = nA3;                                  \
    WA4 = nA4; WA5 = nA5; WA6 = nA6; WA7 = nA7;                                  \
    LamA += onA ? lgA : 0.f;                                                     \
    {                                                                            \
      char* wp = VA[(PAR) ^ 1] + (c << 9);                                       \
      f16x4 h0 = {(_Float16)nA0, (_Float16)nA1, (_Float16)nA2, (_Float16)nA3};   \
      f16x4 h1 = {(_Float16)nA4, (_Float16)nA5, (_Float16)nA6, (_Float16)nA7};   \
      *(f16x4*)(wp + ((64 * w + 8 * s) ^ sw))      = h0;                         \
      *(f16x4*)(wp + ((64 * w + 32 + 8 * s) ^ sw)) = h1;                         \
    }                                                                            \
    { int tn = t_ + 2; if (tn > Tmax - 1) tn = Tmax - 1;                         \
      YA0 = *(const float4*)(ybA + (size_t)tn * KK);                             \
      YA1 = *(const float4*)(ybA + (size_t)tn * KK + 16); }                      \
    /* ---- epilogue B ---- */                                                   \
    const bool onB = (t_ < LciB);                                                \
    f32x4 qB0 = cB0a + cB0b, qB1 = cB1a + cB1b;                                  \
    float nB0 = onB ? __expf(YB0.x) * qB0[0] * gB : WB0;                         \
    float nB1 = onB ? __expf(YB0.y) * qB0[1] * gB : WB1;                         \
    float nB2 = onB ? __expf(YB0.z) * qB0[2] * gB : WB2;                         \
    float nB3 = onB ? __expf(YB0.w) * qB0[3] * gB : WB3;                         \
    float nB4 = onB ? __expf(YB1.x) * qB1[0] * gB : WB4;                         \
    float nB5 = onB ? __expf(YB1.y) * qB1[1] * gB : WB5;                         \
    float nB6 = onB ? __expf(YB1.z) * qB1[2] * gB : WB6;                         \
    float nB7 = onB ? __expf(YB1.w) * qB1[3] * gB : WB7;                         \
    WB0 = nB0; WB1 = nB1; WB2 = nB2; WB3 = nB3;                                  \
    WB4 = nB4; WB5 = nB5; WB6 = nB6; WB7 = nB7;                                  \
    LamB += onB ? lgB : 0.f;                                                     \
    {                                                                            \
      char* wp = VB[(PAR) ^ 1] + (c << 9);                                       \
      f16x4 h0 = {(_Float16)nB0, (_Float16)nB1, (_Float16)nB2, (_Float16)nB3};   \
      f16x4 h1 = {(_Float16)nB4, (_Float16)nB5, (_Float16)nB6, (_Float16)nB7};   \
      *(f16x4*)(wp + ((64 * w + 8 * s) ^ sw))      = h0;                         \
      *(f16x4*)(wp + ((64 * w + 32 + 8 * s) ^ sw)) = h1;                         \
    }                                                                            \
    { int tn = t_ + 2; if (tn > Tmax - 1) tn = Tmax - 1;                         \
      YB0 = *(const float4*)(ybB + (size_t)tn * KK);                             \
      YB1 = *(const float4*)(ybB + (size_t)tn * KK + 16); }                      \
    asm volatile("s_waitcnt lgkmcnt(0)" ::: "memory");                           \
    __builtin_amdgcn_s_barrier();                                                \
    __builtin_amdgcn_sched_barrier(0);                                           \
  }

    int t = 0;
    for (; t + 1 < Tmax; t += 2) {
        INTERVAL(0, yAa0, yAa1, yBa0, yBa1, t);
        INTERVAL(1, yAb0, yAb1, yBb0, yBb1, t + 1);
    }
    if (t < Tmax) INTERVAL(0, yAa0, yAa1, yBa0, yBa1, t);

#undef INTERVAL

    // ---- epilogue: Sigma over final V (wave 0: chain A, wave 1: chain B)
    const int fin = Tmax & 1;
    if (w == 0) {
        const char* vp = VA[fin] + (c << 9);
        f16x8 e0 = *(const f16x8*)(vp + ((0   + (s << 4)) ^ sw));
        f16x8 e1 = *(const f16x8*)(vp + ((64  + (s << 4)) ^ sw));
        f16x8 e2 = *(const f16x8*)(vp + ((128 + (s << 4)) ^ sw));
        f16x8 e3 = *(const f16x8*)(vp + ((192 + (s << 4)) ^ sw));
        f16x8 e4 = *(const f16x8*)(vp + ((256 + (s << 4)) ^ sw));
        f16x8 e5 = *(const f16x8*)(vp + ((320 + (s << 4)) ^ sw));
        f16x8 e6 = *(const f16x8*)(vp + ((384 + (s << 4)) ^ sw));
        f16x8 e7 = *(const f16x8*)(vp + ((448 + (s << 4)) ^ sw));
        f16x8 tc = ((e0 + e1) + (e2 + e3)) + ((e4 + e5) + (e6 + e7));
        f16x2 u0 = {tc[0], tc[1]}, u1 = {tc[2], tc[3]};
        f16x2 u2 = {tc[4], tc[5]}, u3 = {tc[6], tc[7]};
        f16x2 uu = (u0 + u1) + (u2 + u3);
        float Sf = (float)uu[0] + (float)uu[1];
        Sf += __shfl_xor(Sf, 16, 64);
        Sf += __shfl_xor(Sf, 32, 64);
        if (l < 16)
            out[bb + c] = 0.69314718056f * (LamA + __log2f(Sf) + 5.0f * (float)LciA);
    } else if (w == 1) {
        const char* vp = VB[fin] + (c << 9);
        f16x8 e0 = *(const f16x8*)(vp + ((0   + (s << 4)) ^ sw));
        f16x8 e1 = *(const f16x8*)(vp + ((64  + (s << 4)) ^ sw));
        f16x8 e2 = *(const f16x8*)(vp + ((128 + (s << 4)) ^ sw));
        f16x8 e3 = *(const f16x8*)(vp + ((192 + (s << 4)) ^ sw));
        f16x8 e4 = *(const f16x8*)(vp + ((256 + (s << 4)) ^ sw));
        f16x8 e5 = *(const f16x8*)(vp + ((320 + (s << 4)) ^ sw));
        f16x8 e6 = *(const f16x8*)(vp + ((384 + (s << 4)) ^ sw));
        f16x8 e7 = *(const f16x8*)(vp + ((448 + (s << 4)) ^ sw));
        f16x8 tc = ((e0 + e1) + (e2 + e3)) + ((e4 + e5) + (e6 + e7));
        f16x2 u0 = {tc[0], tc[1]}, u1 = {tc[2], tc[3]};
        f16x2 u2 = {tc[4], tc[5]}, u3 = {tc[6], tc[7]};
        f16x2 uu = (u0 + u1) + (u2 + u3);
        float Sf = (float)uu[0] + (float)uu[1];
        Sf += __shfl_xor(Sf, 16, 64);
        Sf += __shfl_xor(Sf, 32, 64);
        if (l < 16)
            out[bb + 16 + c] = 0.69314718056f * (LamB + __log2f(Sf) + 5.0f * (float)LciB);
    }
}

extern "C" void kernel_launch(void* const* d_in, const int* in_sizes, int n_in,
                              void* d_out, int out_size, void* d_ws, size_t ws_size,
                              hipStream_t stream) {
    const float* y     = (const float*)d_in[0];   // (B, T, K) fp32
    const float* mask  = (const float*)d_in[1];   // (B, T)    fp32
    const float* trans = (const float*)d_in[2];   // (K, K)    fp32
    float* out = (float*)d_out;                   // (B,)      fp32
    const int B = in_sizes[1] / TT;
    crf_fwd_kernel<<<B / 32, NTH, 0, stream>>>(y, mask, trans, out);
}